// Round 13
// baseline (194.996 us; speedup 1.0000x reference)
//
#include <hip/hip_runtime.h>

#define N_NODES 50000
#define N_EDGES 800000
#define F 64
#define NPAD 50048                       // N_NODES padded to multiple of 64
#define NBUCK 196                        // node buckets of 256 (50176 >= 50000)
#define NBLK 256                         // build blocks
#define EPB (N_EDGES / NBLK)             // 3125 edges per build block
#define CAP 5120                         // slots per bucket region (mean 4096 + 16 sigma)
#define BN 128                           // fallback fused block
#define AIDX32(k, n) ((k) * 132 + ((k) >> 3) * 4 + (n))

typedef float f32x4 __attribute__((ext_vector_type(4)));
typedef short bf16x8 __attribute__((ext_vector_type(8)));

__device__ inline unsigned short f2bf(float f) {
    unsigned u = __float_as_uint(f);
    u = (u + 0x7FFFu + ((u >> 16) & 1u)) >> 16;
    return (unsigned short)u;
}
__device__ inline float bf2f(unsigned short u) {
    return __uint_as_float((unsigned)u << 16);
}

// ---- P: weights -> bf16 [f][k] panels; x -> bf16; init bucket cursors ----
__global__ __launch_bounds__(256) void prep_kernel(
    const float* __restrict__ x,
    const float* __restrict__ Wxz0, const float* __restrict__ Wxz1,
    const float* __restrict__ Wxh0, const float* __restrict__ Wxh1,
    const float* __restrict__ Wlin,
    unsigned short* __restrict__ xb, unsigned short* __restrict__ wzT,
    unsigned short* __restrict__ whT, unsigned short* __restrict__ wlT,
    int* __restrict__ gcursC, int* __restrict__ gcursR) {
    int blk = blockIdx.x;
    int t = threadIdx.x;
    if (blk < 80) {
        int gid = blk * 256 + t;
        int m = gid >> 12, idx = gid & 4095;
        int k = idx >> 6, f = idx & 63;
        const float* src;
        unsigned short* dst;
        if (m == 0)      { src = Wxz0; dst = wzT; }
        else if (m == 1) { src = Wxz1; dst = wzT + 4096; }
        else if (m == 2) { src = Wxh0; dst = whT; }
        else if (m == 3) { src = Wxh1; dst = whT + 4096; }
        else             { src = Wlin; dst = wlT; }
        dst[f * 64 + k] = f2bf(src[idx]);
    } else if (blk < 80 + NPAD * 16 / 256) {
        int idx4 = (blk - 80) * 256 + t;             // NPAD*16 items
        int n = idx4 >> 4;
        ushort4 o = make_ushort4(0, 0, 0, 0);
        if (n < N_NODES) {
            float4 v = *(const float4*)&x[idx4 * 4];
            o = make_ushort4(f2bf(v.x), f2bf(v.y), f2bf(v.z), f2bf(v.w));
        }
        *(ushort4*)&xb[idx4 * 4] = o;
    } else {                                          // init bucket cursors
        for (int i = t; i < NBUCK; i += 256) {
            gcursC[i] = i * CAP;
            gcursR[i] = i * CAP;
        }
    }
}

// ---- K1: fused histogram + space-reserve + placement (one kernel) ----
__global__ __launch_bounds__(256) void build_kernel(const int* __restrict__ ei,
                                                    const float* __restrict__ ew,
                                                    int* __restrict__ gcursC,
                                                    int* __restrict__ gcursR,
                                                    uint2* __restrict__ colPart,
                                                    uint2* __restrict__ rowPart) {
    __shared__ int histC[NBUCK], histR[NBUCK];
    __shared__ int cursC[NBUCK], cursR[NBUCK];
    const int t = threadIdx.x, blk = blockIdx.x;
    for (int i = t; i < NBUCK; i += 256) { histC[i] = 0; histR[i] = 0; }
    __syncthreads();
    const int e0 = blk * EPB;
    // pass 1: local histograms
    for (int i = t; i < EPB; i += 256) {
        int e = e0 + i;
        int r = ei[e], c = ei[N_EDGES + e];
        if (r != c) {
            atomicAdd(&histC[c >> 8], 1);
            atomicAdd(&histR[r >> 8], 1);
        }
    }
    __syncthreads();
    // reserve space: one global atomic per (block,bucket) on 392 hot lines
    for (int i = t; i < NBUCK; i += 256) {
        cursC[i] = atomicAdd(&gcursC[i], histC[i]);
        cursR[i] = atomicAdd(&gcursR[i], histR[i]);
    }
    __syncthreads();
    // pass 2: re-read (L2-hot) and scatter into reserved ranges
    for (int i = t; i < EPB; i += 256) {
        int e = e0 + i;
        int r = ei[e], c = ei[N_EDGES + e];
        if (r == c) continue;
        unsigned wbits = __float_as_uint(ew[e]);
        int bC = c >> 8, bR = r >> 8;
        int pC = atomicAdd(&cursC[bC], 1);
        if (pC < (bC + 1) * CAP)                      // clamp (never hit: 16 sigma)
            colPart[pC] = make_uint2((unsigned)r | ((unsigned)(c & 255) << 16), wbits);
        int pR = atomicAdd(&cursR[bR], 1);
        if (pR < (bR + 1) * CAP)
            rowPart[pR] = make_uint2((unsigned)(r & 255), wbits);
    }
}

// ---- K2: per-bucket deg reduction (LDS fp32) -> dinv ----
__global__ __launch_bounds__(256) void rowB_kernel(const uint2* __restrict__ rowPart,
                                                   const int* __restrict__ gcursR,
                                                   float* __restrict__ dinv) {
    __shared__ float degL[256];
    const int t = threadIdx.x, b = blockIdx.x;
    degL[t] = 0.0f;
    __syncthreads();
    const int start = b * CAP, end = gcursR[b];
    for (int i = start + t; i < end; i += 256) {
        uint2 v = rowPart[i];
        atomicAdd(&degL[v.x], __uint_as_float(v.y));
    }
    __syncthreads();
    int n = b * 256 + t;
    if (n < N_NODES) {
        float d = degL[t];
        dinv[n] = (d > 0.0f) ? rsqrtf(d) : 0.0f;
    }
}

// ---- K3: per-bucket CSR build in CAP-strided region; fold dinv[row] ----
__global__ __launch_bounds__(256) void colB_kernel(const uint2* __restrict__ colPart,
                                                   const int* __restrict__ gcursC,
                                                   const float* __restrict__ dinv,
                                                   int* __restrict__ offs,
                                                   uint2* __restrict__ edgesOut) {
    __shared__ int cntL[256];
    __shared__ int curL[256];
    __shared__ int wsum[4];
    const int t = threadIdx.x, b = blockIdx.x;
    const int lane = t & 63, wid = t >> 6;
    const int start = b * CAP, end = gcursC[b];
    const int cntB = end - start;
    cntL[t] = 0;
    __syncthreads();
    for (int i = start + t; i < end; i += 256) {
        uint2 v = colPart[i];
        atomicAdd(&cntL[(v.x >> 16) & 255], 1);
    }
    __syncthreads();
    int v = cntL[t];
    int s = v;
#pragma unroll
    for (int d = 1; d < 64; d <<= 1) {
        int u = __shfl_up(s, d);
        if (lane >= d) s += u;
    }
    if (lane == 63) wsum[wid] = s;
    __syncthreads();
    int wbase = 0;
    for (int w = 0; w < wid; ++w) wbase += wsum[w];
    int excl = wbase + s - v;
    curL[t] = excl;
    int n = b * 256 + t;
    if (n <= N_NODES) offs[n] = start + excl;   // includes offs[50000] sentinel
    __syncthreads();
    for (int i = start + t; i < end; i += 256) {
        uint2 e = colPart[i];
        int cl = (e.x >> 16) & 255;
        int p = atomicAdd(&curL[cl], 1);
        int r = e.x & 0xFFFF;
        float wd = __uint_as_float(e.y) * dinv[r];
        edgesOut[start + p] = make_uint2((unsigned)r, __float_as_uint(wd));
    }
    // zero-fill slack so offs[n+1] across bucket boundary reads w=0 entries
    for (int i = cntB + t; i < CAP; i += 256)
        edgesOut[start + i] = make_uint2(0u, 0u);
}

// ---- K4: CSR gather in bf16, wave-uniform loop (all lanes active at shfl) ----
__global__ __launch_bounds__(256) void gather_kernel(const int* __restrict__ offs,
                                                     const uint2* __restrict__ edgesOut,
                                                     const float* __restrict__ dinv,
                                                     const unsigned short* __restrict__ xb,
                                                     unsigned short* __restrict__ Sb) {
    int n = blockIdx.x * 4 + (threadIdx.x >> 6);
    int lane = threadIdx.x & 63;
    if (n >= N_NODES) return;
    const int half = lane >> 5, hl = lane & 31;
    int p = offs[n], end = offs[n + 1];
    float acc0 = 0.0f, acc1 = 0.0f;
    for (int base = p; base < end; base += 64) {
        int rem = end - base;
        uint2 ev = make_uint2(0u, 0u);
        if (lane < rem) ev = edgesOut[base + lane];   // 512B coalesced
        int myr = (int)ev.x;
        float mwd = __uint_as_float(ev.y);
        int cnt = min(rem, 64);
        int j = 0;
        for (; j + 8 <= cnt; j += 8) {                // 4 edges per half
            int sA = j + half,     sB = j + 2 + half;
            int sC = j + 4 + half, sD = j + 6 + half;
            int   rA = __shfl(myr, sA); float wA = __shfl(mwd, sA);
            int   rB = __shfl(myr, sB); float wB = __shfl(mwd, sB);
            int   rC = __shfl(myr, sC); float wC = __shfl(mwd, sC);
            int   rD = __shfl(myr, sD); float wD = __shfl(mwd, sD);
            ushort2 xA = *(const ushort2*)&xb[(size_t)rA * F + hl * 2];
            ushort2 xB = *(const ushort2*)&xb[(size_t)rB * F + hl * 2];
            ushort2 xC = *(const ushort2*)&xb[(size_t)rC * F + hl * 2];
            ushort2 xD = *(const ushort2*)&xb[(size_t)rD * F + hl * 2];
            acc0 = fmaf(wA, bf2f(xA.x), acc0); acc1 = fmaf(wA, bf2f(xA.y), acc1);
            acc0 = fmaf(wB, bf2f(xB.x), acc0); acc1 = fmaf(wB, bf2f(xB.y), acc1);
            acc0 = fmaf(wC, bf2f(xC.x), acc0); acc1 = fmaf(wC, bf2f(xC.y), acc1);
            acc0 = fmaf(wD, bf2f(xD.x), acc0); acc1 = fmaf(wD, bf2f(xD.y), acc1);
        }
        for (; j < cnt; j += 2) {                     // uniform tail
            int s = j + half;
            int r = __shfl(myr, s);
            float wd = __shfl(mwd, s);
            ushort2 xv = *(const ushort2*)&xb[(size_t)r * F + hl * 2];
            acc0 = fmaf(wd, bf2f(xv.x), acc0);
            acc1 = fmaf(wd, bf2f(xv.y), acc1);
        }
    }
    acc0 += __shfl_xor(acc0, 32);
    acc1 += __shfl_xor(acc1, 32);
    if (half == 0) {
        float s = -dinv[n];
        ushort2 o = make_ushort2(f2bf(s * acc0), f2bf(s * acc1));
        *(ushort2*)&Sb[(size_t)n * F + hl * 2] = o;
    }
}

// ---- K5: MFMA fused kernel. 4 waves/block, 16 nodes/wave, no barriers ----
__global__ __launch_bounds__(256) void fused_mfma(
    const unsigned short* __restrict__ xb, const unsigned short* __restrict__ Sb,
    const unsigned short* __restrict__ wzT, const unsigned short* __restrict__ whT,
    const unsigned short* __restrict__ wlT,
    const float* __restrict__ bxz, const float* __restrict__ bhz,
    const float* __restrict__ bxh, const float* __restrict__ bhh,
    const float* __restrict__ blin, float* __restrict__ out) {
    __shared__ __align__(16) unsigned short Rlds[4 * 16 * 72];  // 9.2 KB

    const int t = threadIdx.x;
    const int l = t & 63, wid = t >> 6;
    const int row16 = l & 15, quad = l >> 4;
    const int gn0 = blockIdx.x * 64 + wid * 16;

    f32x4 zacc[4], hacc[4];
#pragma unroll
    for (int ft = 0; ft < 4; ++ft) {
        int f = ft * 16 + row16;
        float bz = bxz[f] + bhz[f];
        float bh = bxh[f] + bhh[f];
        zacc[ft] = (f32x4){bz, bz, bz, bz};
        hacc[ft] = (f32x4){bh, bh, bh, bh};
    }

#pragma unroll
    for (int half = 0; half < 2; ++half) {
        const unsigned short* Ab = half ? Sb : xb;
        const unsigned short* Wzp = wzT + half * 4096;
        const unsigned short* Whp = whT + half * 4096;
#pragma unroll
        for (int ks = 0; ks < 2; ++ks) {
            bf16x8 a = *(const bf16x8*)(Ab + (size_t)(gn0 + row16) * 64 + ks * 32 + quad * 8);
#pragma unroll
            for (int ft = 0; ft < 4; ++ft) {
                bf16x8 bz8 = *(const bf16x8*)(Wzp + (ft * 16 + row16) * 64 + ks * 32 + quad * 8);
                bf16x8 bh8 = *(const bf16x8*)(Whp + (ft * 16 + row16) * 64 + ks * 32 + quad * 8);
                zacc[ft] = __builtin_amdgcn_mfma_f32_16x16x32_bf16(a, bz8, zacc[ft], 0, 0, 0);
                hacc[ft] = __builtin_amdgcn_mfma_f32_16x16x32_bf16(a, bh8, hacc[ft], 0, 0, 0);
            }
        }
    }

#pragma unroll
    for (int ft = 0; ft < 4; ++ft)
#pragma unroll
        for (int r = 0; r < 4; ++r) {
            float z = zacc[ft][r], h = hacc[ft][r];
            float zz = 1.0f / (1.0f + __expf(-z));
            float R = fmaxf((1.0f - zz) * tanhf(h), 0.0f);
            Rlds[wid * 1152 + (quad * 4 + r) * 72 + ft * 16 + row16] = f2bf(R);
        }

    f32x4 oacc[4];
#pragma unroll
    for (int ft = 0; ft < 4; ++ft) oacc[ft] = (f32x4){0.f, 0.f, 0.f, 0.f};
#pragma unroll
    for (int ks = 0; ks < 2; ++ks) {
        bf16x8 ra = *(const bf16x8*)&Rlds[wid * 1152 + row16 * 72 + ks * 32 + quad * 8];
#pragma unroll
        for (int ft = 0; ft < 4; ++ft) {
            bf16x8 wl8 = *(const bf16x8*)(wlT + (ft * 16 + row16) * 64 + ks * 32 + quad * 8);
            oacc[ft] = __builtin_amdgcn_mfma_f32_16x16x32_bf16(ra, wl8, oacc[ft], 0, 0, 0);
        }
    }
#pragma unroll
    for (int ft = 0; ft < 4; ++ft) {
        float bl = blin[ft * 16 + row16];
#pragma unroll
        for (int r = 0; r < 4; ++r) {
            int gn = gn0 + quad * 4 + r;
            if (gn < N_NODES) out[gn * 64 + ft * 16 + row16] = oacc[ft][r] + bl;
        }
    }
}

// ======================= fallback path (ws too small) =======================
__global__ __launch_bounds__(256) void deg_fb(const int* __restrict__ ei,
                                              const float* __restrict__ ew,
                                              float* __restrict__ deg) {
    int e = blockIdx.x * blockDim.x + threadIdx.x;
    if (e >= N_EDGES) return;
    int r = ei[e];
    int c = ei[N_EDGES + e];
    if (r != c) atomicAdd(&deg[r], ew[e]);
}

__global__ __launch_bounds__(256) void dinv_kernel(const float* __restrict__ deg,
                                                   float* __restrict__ dinv) {
    int n = blockIdx.x * blockDim.x + threadIdx.x;
    if (n >= N_NODES) return;
    float d = deg[n];
    dinv[n] = (d > 0.0f) ? rsqrtf(d) : 0.0f;
}

__global__ __launch_bounds__(256) void scatter_fb(const int* __restrict__ ei,
                                                  const float* __restrict__ ew,
                                                  const float* __restrict__ x,
                                                  const float* __restrict__ dinv,
                                                  float* S) {
    int e = blockIdx.x * 4 + (threadIdx.x >> 6);
    int lane = threadIdx.x & 63;
    if (e >= N_EDGES) return;
    int r = ei[e];
    int c = ei[N_EDGES + e];
    if (r == c) return;
    float nrm = -dinv[r] * ew[e] * dinv[c];
    atomicAdd(&S[c * F + lane], nrm * x[r * F + lane]);
}

__global__ __launch_bounds__(128) void fused_fp32(
    const float* __restrict__ x, float* sOut,
    const float* __restrict__ Wxz0, const float* __restrict__ Wxz1,
    const float* __restrict__ Wxh0, const float* __restrict__ Wxh1,
    const float* __restrict__ bxz, const float* __restrict__ bhz,
    const float* __restrict__ bxh, const float* __restrict__ bhh,
    const float* __restrict__ Wlin, const float* __restrict__ blin) {
    __shared__ float P[8448];
    float* As = P;
    float* Wc = P + 4352;
    const int t = threadIdx.x;
    const int n0 = blockIdx.x * BN;
    const int ti = t >> 3;
    const int tj = t & 7;
    const int nb = ti * 8;
    const int f0 = tj * 8;

    float zacc[8][8], hacc[8][8];
#pragma unroll
    for (int j = 0; j < 8; ++j) {
        float bz = bxz[f0 + j] + bhz[f0 + j];
        float bh = bxh[f0 + j] + bhh[f0 + j];
#pragma unroll
        for (int i = 0; i < 8; ++i) { zacc[i][j] = bz; hacc[i][j] = bh; }
    }
    for (int half = 0; half < 2; ++half) {
        const float* Abase = half ? (const float*)sOut : x;
        const float* Wz = half ? Wxz1 : Wxz0;
        const float* Wh = half ? Wxh1 : Wxh0;
        for (int kc = 0; kc < 2; ++kc) {
            const int kb = kc * 32;
            __syncthreads();
#pragma unroll
            for (int rep = 0; rep < 8; ++rep) {
                int idx = rep * 128 + t;
                int nn = idx >> 3;
                int q = idx & 7;
                int gn = n0 + nn;
                float4 v = make_float4(0.f, 0.f, 0.f, 0.f);
                if (gn < N_NODES) v = *(const float4*)&Abase[gn * F + kb + q * 4];
                int k = q * 4;
                As[AIDX32(k + 0, nn)] = v.x;
                As[AIDX32(k + 1, nn)] = v.y;
                As[AIDX32(k + 2, nn)] = v.z;
                As[AIDX32(k + 3, nn)] = v.w;
            }
#pragma unroll
            for (int rep = 0; rep < 8; ++rep) {
                int idx = rep * 128 + t;
                int cq = idx & 31;
                int kk = idx >> 5;
                const float* src = (cq < 16) ? &Wz[(kb + kk) * F + cq * 4]
                                             : &Wh[(kb + kk) * F + (cq - 16) * 4];
                *(float4*)&Wc[kk * 128 + cq * 4] = *(const float4*)src;
            }
            __syncthreads();
#pragma unroll 8
            for (int kl = 0; kl < 32; ++kl) {
                const float* Ap = &As[AIDX32(kl, nb)];
                float4 a0 = *(const float4*)Ap;
                float4 a1 = *(const float4*)(Ap + 4);
                const float* Wp = &Wc[kl * 128 + f0];
                float4 wz0 = *(const float4*)Wp;
                float4 wz1 = *(const float4*)(Wp + 4);
                float4 wh0 = *(const float4*)(Wp + 64);
                float4 wh1 = *(const float4*)(Wp + 68);
                float a[8]  = {a0.x, a0.y, a0.z, a0.w, a1.x, a1.y, a1.z, a1.w};
                float wz[8] = {wz0.x, wz0.y, wz0.z, wz0.w, wz1.x, wz1.y, wz1.z, wz1.w};
                float wh[8] = {wh0.x, wh0.y, wh0.z, wh0.w, wh1.x, wh1.y, wh1.z, wh1.w};
#pragma unroll
                for (int i = 0; i < 8; ++i)
#pragma unroll
                    for (int j = 0; j < 8; ++j) {
                        zacc[i][j] = fmaf(a[i], wz[j], zacc[i][j]);
                        hacc[i][j] = fmaf(a[i], wh[j], hacc[i][j]);
                    }
            }
        }
    }
    __syncthreads();
#pragma unroll
    for (int j = 0; j < 8; ++j) {
        int f = f0 + j;
        float R[8];
#pragma unroll
        for (int i = 0; i < 8; ++i) {
            float zz = 1.0f / (1.0f + __expf(-zacc[i][j]));
            float hh = tanhf(hacc[i][j]);
            R[i] = fmaxf((1.0f - zz) * hh, 0.0f);
        }
        float* Rp = &P[f * 132 + nb];
        *(float4*)Rp = make_float4(R[0], R[1], R[2], R[3]);
        *(float4*)(Rp + 4) = make_float4(R[4], R[5], R[6], R[7]);
    }
    __syncthreads();
    float (*oacc)[8] = zacc;
#pragma unroll
    for (int j = 0; j < 8; ++j) {
        float bl = blin[f0 + j];
#pragma unroll
        for (int i = 0; i < 8; ++i) oacc[i][j] = bl;
    }
#pragma unroll 4
    for (int k = 0; k < 64; ++k) {
        const float* Rp = &P[k * 132 + nb];
        float4 a0 = *(const float4*)Rp;
        float4 a1 = *(const float4*)(Rp + 4);
        float4 w0 = *(const float4*)&Wlin[k * F + f0];
        float4 w1 = *(const float4*)&Wlin[k * F + f0 + 4];
        float a[8] = {a0.x, a0.y, a0.z, a0.w, a1.x, a1.y, a1.z, a1.w};
        float w[8] = {w0.x, w0.y, w0.z, w0.w, w1.x, w1.y, w1.z, w1.w};
#pragma unroll
        for (int i = 0; i < 8; ++i)
#pragma unroll
            for (int j = 0; j < 8; ++j)
                oacc[i][j] = fmaf(a[i], w[j], oacc[i][j]);
    }
#pragma unroll
    for (int i = 0; i < 8; ++i) {
        int gn = n0 + nb + i;
        if (gn < N_NODES) {
            *(float4*)&sOut[gn * F + f0] =
                make_float4(oacc[i][0], oacc[i][1], oacc[i][2], oacc[i][3]);
            *(float4*)&sOut[gn * F + f0 + 4] =
                make_float4(oacc[i][4], oacc[i][5], oacc[i][6], oacc[i][7]);
        }
    }
}

extern "C" void kernel_launch(void* const* d_in, const int* in_sizes, int n_in,
                              void* d_out, int out_size, void* d_ws, size_t ws_size,
                              hipStream_t stream) {
    const float* x    = (const float*)d_in[0];
    const int*   ei   = (const int*)d_in[1];
    const float* ew   = (const float*)d_in[2];
    const float* Wxz0 = (const float*)d_in[3];
    const float* Wxz1 = (const float*)d_in[4];
    const float* bxz  = (const float*)d_in[5];
    const float* bhz  = (const float*)d_in[8];
    const float* Wxh0 = (const float*)d_in[15];
    const float* Wxh1 = (const float*)d_in[16];
    const float* bxh  = (const float*)d_in[17];
    const float* bhh  = (const float*)d_in[20];
    const float* Wlin = (const float*)d_in[21];
    const float* blin = (const float*)d_in[22];
    float* outp = (float*)d_out;

    int*    gcursC = (int*)d_ws;                 // NBUCK
    int*    gcursR = gcursC + 256;               // NBUCK
    int*    offs   = gcursR + 256;               // NPAD+64
    float*  dinv   = (float*)(offs + NPAD + 64); // NPAD
    unsigned short* xb  = (unsigned short*)(dinv + NPAD);
    unsigned short* Sb  = xb + (size_t)NPAD * 64;
    unsigned short* wzT = Sb + (size_t)NPAD * 64;
    unsigned short* whT = wzT + 8192;
    unsigned short* wlT = whT + 8192;
    uint2*  colPart  = (uint2*)(wlT + 4096);
    uint2*  rowPart  = colPart + (size_t)NBUCK * CAP;
    uint2*  edgesOut = rowPart + (size_t)NBUCK * CAP;
    size_t needed = (size_t)(512 + NPAD + 64 + NPAD) * 4
                  + (size_t)NPAD * 64 * 2 * 2 + 40960
                  + (size_t)NBUCK * CAP * 3 * 8 + 256;

    if (ws_size >= needed) {
        prep_kernel<<<80 + NPAD * 16 / 256 + 1, 256, 0, stream>>>(
            x, Wxz0, Wxz1, Wxh0, Wxh1, Wlin, xb, wzT, whT, wlT, gcursC, gcursR);
        build_kernel<<<NBLK, 256, 0, stream>>>(ei, ew, gcursC, gcursR,
                                               colPart, rowPart);
        rowB_kernel<<<NBUCK, 256, 0, stream>>>(rowPart, gcursR, dinv);
        colB_kernel<<<NBUCK, 256, 0, stream>>>(colPart, gcursC, dinv, offs, edgesOut);
        gather_kernel<<<(N_NODES + 3) / 4, 256, 0, stream>>>(offs, edgesOut, dinv,
                                                             xb, Sb);
        fused_mfma<<<NPAD / 64, 256, 0, stream>>>(xb, Sb, wzT, whT, wlT,
                                                  bxz, bhz, bxh, bhh, blin, outp);
    } else {
        float* deg = (float*)d_ws;
        float* dv  = deg + NPAD;
        hipMemsetAsync(deg, 0, (size_t)NPAD * sizeof(float), stream);
        hipMemsetAsync(d_out, 0, (size_t)N_NODES * F * sizeof(float), stream);
        deg_fb<<<(N_EDGES + 255) / 256, 256, 0, stream>>>(ei, ew, deg);
        dinv_kernel<<<(N_NODES + 255) / 256, 256, 0, stream>>>(deg, dv);
        scatter_fb<<<N_EDGES / 4, 256, 0, stream>>>(ei, ew, x, dv, outp);
        fused_fp32<<<(N_NODES + BN - 1) / BN, 128, 0, stream>>>(
            x, outp, Wxz0, Wxz1, Wxh0, Wxh1, bxz, bhz, bxh, bhh, Wlin, blin);
    }
}

// Round 14
// 109.254 us; speedup vs baseline: 1.7848x; 1.7848x over previous
//
#include <hip/hip_runtime.h>

#define N_NODES 50000
#define N_EDGES 800000
#define F 64
#define NPAD 50048                       // N_NODES padded to multiple of 64
#define NBUCK 196                        // node buckets of 256 (50176 >= 50000)
#define NBLK 256                         // build blocks
#define EPB (N_EDGES / NBLK)             // 3125 edges per build block
#define CAP 5120                         // slots per bucket region (mean 4096 + 16 sigma)
#define BN 128                           // fallback fused block
#define AIDX32(k, n) ((k) * 132 + ((k) >> 3) * 4 + (n))

typedef float f32x4 __attribute__((ext_vector_type(4)));
typedef short bf16x8 __attribute__((ext_vector_type(8)));

__device__ inline unsigned short f2bf(float f) {
    unsigned u = __float_as_uint(f);
    u = (u + 0x7FFFu + ((u >> 16) & 1u)) >> 16;
    return (unsigned short)u;
}
__device__ inline float bf2f(unsigned short u) {
    return __uint_as_float((unsigned)u << 16);
}

// ---- P: weights -> bf16 [f][k] panels; x -> bf16; init bucket cursors ----
__global__ __launch_bounds__(256) void prep_kernel(
    const float* __restrict__ x,
    const float* __restrict__ Wxz0, const float* __restrict__ Wxz1,
    const float* __restrict__ Wxh0, const float* __restrict__ Wxh1,
    const float* __restrict__ Wlin,
    unsigned short* __restrict__ xb, unsigned short* __restrict__ wzT,
    unsigned short* __restrict__ whT, unsigned short* __restrict__ wlT,
    int* __restrict__ gcursC, int* __restrict__ gcursR) {
    int blk = blockIdx.x;
    int t = threadIdx.x;
    if (blk < 80) {
        int gid = blk * 256 + t;
        int m = gid >> 12, idx = gid & 4095;
        int k = idx >> 6, f = idx & 63;
        const float* src;
        unsigned short* dst;
        if (m == 0)      { src = Wxz0; dst = wzT; }
        else if (m == 1) { src = Wxz1; dst = wzT + 4096; }
        else if (m == 2) { src = Wxh0; dst = whT; }
        else if (m == 3) { src = Wxh1; dst = whT + 4096; }
        else             { src = Wlin; dst = wlT; }
        dst[f * 64 + k] = f2bf(src[idx]);
    } else if (blk < 80 + NPAD * 16 / 256) {
        int idx4 = (blk - 80) * 256 + t;             // NPAD*16 items
        int n = idx4 >> 4;
        ushort4 o = make_ushort4(0, 0, 0, 0);
        if (n < N_NODES) {
            float4 v = *(const float4*)&x[idx4 * 4];
            o = make_ushort4(f2bf(v.x), f2bf(v.y), f2bf(v.z), f2bf(v.w));
        }
        *(ushort4*)&xb[idx4 * 4] = o;
    } else {                                          // init bucket cursors
        for (int i = t; i < NBUCK; i += 256) {
            gcursC[i] = i * CAP;
            gcursR[i] = i * CAP;
        }
    }
}

// ---- K1: fused histogram + space-reserve + placement (one kernel) ----
__global__ __launch_bounds__(256) void build_kernel(const int* __restrict__ ei,
                                                    const float* __restrict__ ew,
                                                    int* __restrict__ gcursC,
                                                    int* __restrict__ gcursR,
                                                    uint2* __restrict__ colPart,
                                                    uint2* __restrict__ rowPart) {
    __shared__ int histC[NBUCK], histR[NBUCK];
    __shared__ int cursC[NBUCK], cursR[NBUCK];
    const int t = threadIdx.x, blk = blockIdx.x;
    for (int i = t; i < NBUCK; i += 256) { histC[i] = 0; histR[i] = 0; }
    __syncthreads();
    const int e0 = blk * EPB;
    // pass 1: local histograms
    for (int i = t; i < EPB; i += 256) {
        int e = e0 + i;
        int r = ei[e], c = ei[N_EDGES + e];
        if (r != c) {
            atomicAdd(&histC[c >> 8], 1);
            atomicAdd(&histR[r >> 8], 1);
        }
    }
    __syncthreads();
    // reserve space: one global atomic per (block,bucket) on 392 hot lines
    for (int i = t; i < NBUCK; i += 256) {
        cursC[i] = atomicAdd(&gcursC[i], histC[i]);
        cursR[i] = atomicAdd(&gcursR[i], histR[i]);
    }
    __syncthreads();
    // pass 2: re-read (L2-hot) and scatter into reserved ranges
    for (int i = t; i < EPB; i += 256) {
        int e = e0 + i;
        int r = ei[e], c = ei[N_EDGES + e];
        if (r == c) continue;
        unsigned wbits = __float_as_uint(ew[e]);
        int bC = c >> 8, bR = r >> 8;
        int pC = atomicAdd(&cursC[bC], 1);
        if (pC < (bC + 1) * CAP)                      // clamp (never hit: 16 sigma)
            colPart[pC] = make_uint2((unsigned)r | ((unsigned)(c & 255) << 16), wbits);
        int pR = atomicAdd(&cursR[bR], 1);
        if (pR < (bR + 1) * CAP)
            rowPart[pR] = make_uint2((unsigned)(r & 255), wbits);
    }
}

// ---- K2: per-bucket deg reduction (LDS fp32) -> dinv ----
__global__ __launch_bounds__(256) void rowB_kernel(const uint2* __restrict__ rowPart,
                                                   const int* __restrict__ gcursR,
                                                   float* __restrict__ dinv) {
    __shared__ float degL[256];
    const int t = threadIdx.x, b = blockIdx.x;
    degL[t] = 0.0f;
    __syncthreads();
    const int start = b * CAP, end = gcursR[b];
    for (int i = start + t; i < end; i += 256) {
        uint2 v = rowPart[i];
        atomicAdd(&degL[v.x], __uint_as_float(v.y));
    }
    __syncthreads();
    int n = b * 256 + t;
    if (n < N_NODES) {
        float d = degL[t];
        dinv[n] = (d > 0.0f) ? rsqrtf(d) : 0.0f;
    }
}

// ---- K3: per-bucket CSR build in CAP-strided region; fold dinv[row];
//      per-node start (offs) AND exact count (ecnt) -- no neighbor deref ----
__global__ __launch_bounds__(256) void colB_kernel(const uint2* __restrict__ colPart,
                                                   const int* __restrict__ gcursC,
                                                   const float* __restrict__ dinv,
                                                   int* __restrict__ offs,
                                                   int* __restrict__ ecnt,
                                                   uint2* __restrict__ edgesOut) {
    __shared__ int cntL[256];
    __shared__ int curL[256];
    __shared__ int wsum[4];
    const int t = threadIdx.x, b = blockIdx.x;
    const int lane = t & 63, wid = t >> 6;
    const int start = b * CAP, end = gcursC[b];
    cntL[t] = 0;
    __syncthreads();
    for (int i = start + t; i < end; i += 256) {
        uint2 v = colPart[i];
        atomicAdd(&cntL[(v.x >> 16) & 255], 1);
    }
    __syncthreads();
    int v = cntL[t];
    int s = v;
#pragma unroll
    for (int d = 1; d < 64; d <<= 1) {
        int u = __shfl_up(s, d);
        if (lane >= d) s += u;
    }
    if (lane == 63) wsum[wid] = s;
    __syncthreads();
    int wbase = 0;
    for (int w = 0; w < wid; ++w) wbase += wsum[w];
    int excl = wbase + s - v;
    curL[t] = excl;
    int n = b * 256 + t;
    if (n < N_NODES) { offs[n] = start + excl; ecnt[n] = v; }
    __syncthreads();
    for (int i = start + t; i < end; i += 256) {
        uint2 e = colPart[i];
        int cl = (e.x >> 16) & 255;
        int p = atomicAdd(&curL[cl], 1);
        int r = e.x & 0xFFFF;
        float wd = __uint_as_float(e.y) * dinv[r];
        edgesOut[start + p] = make_uint2((unsigned)r, __float_as_uint(wd));
    }
}

// ---- K4: CSR gather in bf16, wave-uniform loop (all lanes active at shfl) ----
__global__ __launch_bounds__(256) void gather_kernel(const int* __restrict__ offs,
                                                     const int* __restrict__ ecnt,
                                                     const uint2* __restrict__ edgesOut,
                                                     const float* __restrict__ dinv,
                                                     const unsigned short* __restrict__ xb,
                                                     unsigned short* __restrict__ Sb) {
    int n = blockIdx.x * 4 + (threadIdx.x >> 6);
    int lane = threadIdx.x & 63;
    if (n >= N_NODES) return;
    const int half = lane >> 5, hl = lane & 31;
    int p = offs[n];
    int end = p + ecnt[n];                            // exact count: no slack
    float acc0 = 0.0f, acc1 = 0.0f;
    for (int base = p; base < end; base += 64) {
        int rem = end - base;
        uint2 ev = make_uint2(0u, 0u);
        if (lane < rem) ev = edgesOut[base + lane];   // 512B coalesced
        int myr = (int)ev.x;
        float mwd = __uint_as_float(ev.y);
        int cnt = min(rem, 64);
        int j = 0;
        for (; j + 8 <= cnt; j += 8) {                // 4 edges per half
            int sA = j + half,     sB = j + 2 + half;
            int sC = j + 4 + half, sD = j + 6 + half;
            int   rA = __shfl(myr, sA); float wA = __shfl(mwd, sA);
            int   rB = __shfl(myr, sB); float wB = __shfl(mwd, sB);
            int   rC = __shfl(myr, sC); float wC = __shfl(mwd, sC);
            int   rD = __shfl(myr, sD); float wD = __shfl(mwd, sD);
            ushort2 xA = *(const ushort2*)&xb[(size_t)rA * F + hl * 2];
            ushort2 xB = *(const ushort2*)&xb[(size_t)rB * F + hl * 2];
            ushort2 xC = *(const ushort2*)&xb[(size_t)rC * F + hl * 2];
            ushort2 xD = *(const ushort2*)&xb[(size_t)rD * F + hl * 2];
            acc0 = fmaf(wA, bf2f(xA.x), acc0); acc1 = fmaf(wA, bf2f(xA.y), acc1);
            acc0 = fmaf(wB, bf2f(xB.x), acc0); acc1 = fmaf(wB, bf2f(xB.y), acc1);
            acc0 = fmaf(wC, bf2f(xC.x), acc0); acc1 = fmaf(wC, bf2f(xC.y), acc1);
            acc0 = fmaf(wD, bf2f(xD.x), acc0); acc1 = fmaf(wD, bf2f(xD.y), acc1);
        }
        for (; j < cnt; j += 2) {                     // uniform tail
            int s = j + half;
            int r = __shfl(myr, s);
            float wd = __shfl(mwd, s);
            ushort2 xv = *(const ushort2*)&xb[(size_t)r * F + hl * 2];
            acc0 = fmaf(wd, bf2f(xv.x), acc0);
            acc1 = fmaf(wd, bf2f(xv.y), acc1);
        }
    }
    acc0 += __shfl_xor(acc0, 32);
    acc1 += __shfl_xor(acc1, 32);
    if (half == 0) {
        float s = -dinv[n];
        ushort2 o = make_ushort2(f2bf(s * acc0), f2bf(s * acc1));
        *(ushort2*)&Sb[(size_t)n * F + hl * 2] = o;
    }
}

// ---- K5: MFMA fused kernel. 4 waves/block, 16 nodes/wave, no barriers ----
__global__ __launch_bounds__(256) void fused_mfma(
    const unsigned short* __restrict__ xb, const unsigned short* __restrict__ Sb,
    const unsigned short* __restrict__ wzT, const unsigned short* __restrict__ whT,
    const unsigned short* __restrict__ wlT,
    const float* __restrict__ bxz, const float* __restrict__ bhz,
    const float* __restrict__ bxh, const float* __restrict__ bhh,
    const float* __restrict__ blin, float* __restrict__ out) {
    __shared__ __align__(16) unsigned short Rlds[4 * 16 * 72];  // 9.2 KB

    const int t = threadIdx.x;
    const int l = t & 63, wid = t >> 6;
    const int row16 = l & 15, quad = l >> 4;
    const int gn0 = blockIdx.x * 64 + wid * 16;

    f32x4 zacc[4], hacc[4];
#pragma unroll
    for (int ft = 0; ft < 4; ++ft) {
        int f = ft * 16 + row16;
        float bz = bxz[f] + bhz[f];
        float bh = bxh[f] + bhh[f];
        zacc[ft] = (f32x4){bz, bz, bz, bz};
        hacc[ft] = (f32x4){bh, bh, bh, bh};
    }

#pragma unroll
    for (int half = 0; half < 2; ++half) {
        const unsigned short* Ab = half ? Sb : xb;
        const unsigned short* Wzp = wzT + half * 4096;
        const unsigned short* Whp = whT + half * 4096;
#pragma unroll
        for (int ks = 0; ks < 2; ++ks) {
            bf16x8 a = *(const bf16x8*)(Ab + (size_t)(gn0 + row16) * 64 + ks * 32 + quad * 8);
#pragma unroll
            for (int ft = 0; ft < 4; ++ft) {
                bf16x8 bz8 = *(const bf16x8*)(Wzp + (ft * 16 + row16) * 64 + ks * 32 + quad * 8);
                bf16x8 bh8 = *(const bf16x8*)(Whp + (ft * 16 + row16) * 64 + ks * 32 + quad * 8);
                zacc[ft] = __builtin_amdgcn_mfma_f32_16x16x32_bf16(a, bz8, zacc[ft], 0, 0, 0);
                hacc[ft] = __builtin_amdgcn_mfma_f32_16x16x32_bf16(a, bh8, hacc[ft], 0, 0, 0);
            }
        }
    }

#pragma unroll
    for (int ft = 0; ft < 4; ++ft)
#pragma unroll
        for (int r = 0; r < 4; ++r) {
            float z = zacc[ft][r], h = hacc[ft][r];
            float zz = 1.0f / (1.0f + __expf(-z));
            float R = fmaxf((1.0f - zz) * tanhf(h), 0.0f);
            Rlds[wid * 1152 + (quad * 4 + r) * 72 + ft * 16 + row16] = f2bf(R);
        }

    f32x4 oacc[4];
#pragma unroll
    for (int ft = 0; ft < 4; ++ft) oacc[ft] = (f32x4){0.f, 0.f, 0.f, 0.f};
#pragma unroll
    for (int ks = 0; ks < 2; ++ks) {
        bf16x8 ra = *(const bf16x8*)&Rlds[wid * 1152 + row16 * 72 + ks * 32 + quad * 8];
#pragma unroll
        for (int ft = 0; ft < 4; ++ft) {
            bf16x8 wl8 = *(const bf16x8*)(wlT + (ft * 16 + row16) * 64 + ks * 32 + quad * 8);
            oacc[ft] = __builtin_amdgcn_mfma_f32_16x16x32_bf16(ra, wl8, oacc[ft], 0, 0, 0);
        }
    }
#pragma unroll
    for (int ft = 0; ft < 4; ++ft) {
        float bl = blin[ft * 16 + row16];
#pragma unroll
        for (int r = 0; r < 4; ++r) {
            int gn = gn0 + quad * 4 + r;
            if (gn < N_NODES) out[gn * 64 + ft * 16 + row16] = oacc[ft][r] + bl;
        }
    }
}

// ======================= fallback path (ws too small) =======================
__global__ __launch_bounds__(256) void deg_fb(const int* __restrict__ ei,
                                              const float* __restrict__ ew,
                                              float* __restrict__ deg) {
    int e = blockIdx.x * blockDim.x + threadIdx.x;
    if (e >= N_EDGES) return;
    int r = ei[e];
    int c = ei[N_EDGES + e];
    if (r != c) atomicAdd(&deg[r], ew[e]);
}

__global__ __launch_bounds__(256) void dinv_kernel(const float* __restrict__ deg,
                                                   float* __restrict__ dinv) {
    int n = blockIdx.x * blockDim.x + threadIdx.x;
    if (n >= N_NODES) return;
    float d = deg[n];
    dinv[n] = (d > 0.0f) ? rsqrtf(d) : 0.0f;
}

__global__ __launch_bounds__(256) void scatter_fb(const int* __restrict__ ei,
                                                  const float* __restrict__ ew,
                                                  const float* __restrict__ x,
                                                  const float* __restrict__ dinv,
                                                  float* S) {
    int e = blockIdx.x * 4 + (threadIdx.x >> 6);
    int lane = threadIdx.x & 63;
    if (e >= N_EDGES) return;
    int r = ei[e];
    int c = ei[N_EDGES + e];
    if (r == c) return;
    float nrm = -dinv[r] * ew[e] * dinv[c];
    atomicAdd(&S[c * F + lane], nrm * x[r * F + lane]);
}

__global__ __launch_bounds__(128) void fused_fp32(
    const float* __restrict__ x, float* sOut,
    const float* __restrict__ Wxz0, const float* __restrict__ Wxz1,
    const float* __restrict__ Wxh0, const float* __restrict__ Wxh1,
    const float* __restrict__ bxz, const float* __restrict__ bhz,
    const float* __restrict__ bxh, const float* __restrict__ bhh,
    const float* __restrict__ Wlin, const float* __restrict__ blin) {
    __shared__ float P[8448];
    float* As = P;
    float* Wc = P + 4352;
    const int t = threadIdx.x;
    const int n0 = blockIdx.x * BN;
    const int ti = t >> 3;
    const int tj = t & 7;
    const int nb = ti * 8;
    const int f0 = tj * 8;

    float zacc[8][8], hacc[8][8];
#pragma unroll
    for (int j = 0; j < 8; ++j) {
        float bz = bxz[f0 + j] + bhz[f0 + j];
        float bh = bxh[f0 + j] + bhh[f0 + j];
#pragma unroll
        for (int i = 0; i < 8; ++i) { zacc[i][j] = bz; hacc[i][j] = bh; }
    }
    for (int half = 0; half < 2; ++half) {
        const float* Abase = half ? (const float*)sOut : x;
        const float* Wz = half ? Wxz1 : Wxz0;
        const float* Wh = half ? Wxh1 : Wxh0;
        for (int kc = 0; kc < 2; ++kc) {
            const int kb = kc * 32;
            __syncthreads();
#pragma unroll
            for (int rep = 0; rep < 8; ++rep) {
                int idx = rep * 128 + t;
                int nn = idx >> 3;
                int q = idx & 7;
                int gn = n0 + nn;
                float4 v = make_float4(0.f, 0.f, 0.f, 0.f);
                if (gn < N_NODES) v = *(const float4*)&Abase[gn * F + kb + q * 4];
                int k = q * 4;
                As[AIDX32(k + 0, nn)] = v.x;
                As[AIDX32(k + 1, nn)] = v.y;
                As[AIDX32(k + 2, nn)] = v.z;
                As[AIDX32(k + 3, nn)] = v.w;
            }
#pragma unroll
            for (int rep = 0; rep < 8; ++rep) {
                int idx = rep * 128 + t;
                int cq = idx & 31;
                int kk = idx >> 5;
                const float* src = (cq < 16) ? &Wz[(kb + kk) * F + cq * 4]
                                             : &Wh[(kb + kk) * F + (cq - 16) * 4];
                *(float4*)&Wc[kk * 128 + cq * 4] = *(const float4*)src;
            }
            __syncthreads();
#pragma unroll 8
            for (int kl = 0; kl < 32; ++kl) {
                const float* Ap = &As[AIDX32(kl, nb)];
                float4 a0 = *(const float4*)Ap;
                float4 a1 = *(const float4*)(Ap + 4);
                const float* Wp = &Wc[kl * 128 + f0];
                float4 wz0 = *(const float4*)Wp;
                float4 wz1 = *(const float4*)(Wp + 4);
                float4 wh0 = *(const float4*)(Wp + 64);
                float4 wh1 = *(const float4*)(Wp + 68);
                float a[8]  = {a0.x, a0.y, a0.z, a0.w, a1.x, a1.y, a1.z, a1.w};
                float wz[8] = {wz0.x, wz0.y, wz0.z, wz0.w, wz1.x, wz1.y, wz1.z, wz1.w};
                float wh[8] = {wh0.x, wh0.y, wh0.z, wh0.w, wh1.x, wh1.y, wh1.z, wh1.w};
#pragma unroll
                for (int i = 0; i < 8; ++i)
#pragma unroll
                    for (int j = 0; j < 8; ++j) {
                        zacc[i][j] = fmaf(a[i], wz[j], zacc[i][j]);
                        hacc[i][j] = fmaf(a[i], wh[j], hacc[i][j]);
                    }
            }
        }
    }
    __syncthreads();
#pragma unroll
    for (int j = 0; j < 8; ++j) {
        int f = f0 + j;
        float R[8];
#pragma unroll
        for (int i = 0; i < 8; ++i) {
            float zz = 1.0f / (1.0f + __expf(-zacc[i][j]));
            float hh = tanhf(hacc[i][j]);
            R[i] = fmaxf((1.0f - zz) * hh, 0.0f);
        }
        float* Rp = &P[f * 132 + nb];
        *(float4*)Rp = make_float4(R[0], R[1], R[2], R[3]);
        *(float4*)(Rp + 4) = make_float4(R[4], R[5], R[6], R[7]);
    }
    __syncthreads();
    float (*oacc)[8] = zacc;
#pragma unroll
    for (int j = 0; j < 8; ++j) {
        float bl = blin[f0 + j];
#pragma unroll
        for (int i = 0; i < 8; ++i) oacc[i][j] = bl;
    }
#pragma unroll 4
    for (int k = 0; k < 64; ++k) {
        const float* Rp = &P[k * 132 + nb];
        float4 a0 = *(const float4*)Rp;
        float4 a1 = *(const float4*)(Rp + 4);
        float4 w0 = *(const float4*)&Wlin[k * F + f0];
        float4 w1 = *(const float4*)&Wlin[k * F + f0 + 4];
        float a[8] = {a0.x, a0.y, a0.z, a0.w, a1.x, a1.y, a1.z, a1.w};
        float w[8] = {w0.x, w0.y, w0.z, w0.w, w1.x, w1.y, w1.z, w1.w};
#pragma unroll
        for (int i = 0; i < 8; ++i)
#pragma unroll
            for (int j = 0; j < 8; ++j)
                oacc[i][j] = fmaf(a[i], w[j], oacc[i][j]);
    }
#pragma unroll
    for (int i = 0; i < 8; ++i) {
        int gn = n0 + nb + i;
        if (gn < N_NODES) {
            *(float4*)&sOut[gn * F + f0] =
                make_float4(oacc[i][0], oacc[i][1], oacc[i][2], oacc[i][3]);
            *(float4*)&sOut[gn * F + f0 + 4] =
                make_float4(oacc[i][4], oacc[i][5], oacc[i][6], oacc[i][7]);
        }
    }
}

extern "C" void kernel_launch(void* const* d_in, const int* in_sizes, int n_in,
                              void* d_out, int out_size, void* d_ws, size_t ws_size,
                              hipStream_t stream) {
    const float* x    = (const float*)d_in[0];
    const int*   ei   = (const int*)d_in[1];
    const float* ew   = (const float*)d_in[2];
    const float* Wxz0 = (const float*)d_in[3];
    const float* Wxz1 = (const float*)d_in[4];
    const float* bxz  = (const float*)d_in[5];
    const float* bhz  = (const float*)d_in[8];
    const float* Wxh0 = (const float*)d_in[15];
    const float* Wxh1 = (const float*)d_in[16];
    const float* bxh  = (const float*)d_in[17];
    const float* bhh  = (const float*)d_in[20];
    const float* Wlin = (const float*)d_in[21];
    const float* blin = (const float*)d_in[22];
    float* outp = (float*)d_out;

    int*    gcursC = (int*)d_ws;                 // NBUCK
    int*    gcursR = gcursC + 256;               // NBUCK
    int*    offs   = gcursR + 256;               // NPAD
    int*    ecnt   = offs + NPAD;                // NPAD
    float*  dinv   = (float*)(ecnt + NPAD);      // NPAD
    unsigned short* xb  = (unsigned short*)(dinv + NPAD);
    unsigned short* Sb  = xb + (size_t)NPAD * 64;
    unsigned short* wzT = Sb + (size_t)NPAD * 64;
    unsigned short* whT = wzT + 8192;
    unsigned short* wlT = whT + 8192;
    uint2*  colPart  = (uint2*)(wlT + 4096);
    uint2*  rowPart  = colPart + (size_t)NBUCK * CAP;
    uint2*  edgesOut = rowPart + (size_t)NBUCK * CAP;
    size_t needed = (size_t)(512 + NPAD * 3) * 4
                  + (size_t)NPAD * 64 * 2 * 2 + 40960
                  + (size_t)NBUCK * CAP * 3 * 8 + 256;

    if (ws_size >= needed) {
        prep_kernel<<<80 + NPAD * 16 / 256 + 1, 256, 0, stream>>>(
            x, Wxz0, Wxz1, Wxh0, Wxh1, Wlin, xb, wzT, whT, wlT, gcursC, gcursR);
        build_kernel<<<NBLK, 256, 0, stream>>>(ei, ew, gcursC, gcursR,
                                               colPart, rowPart);
        rowB_kernel<<<NBUCK, 256, 0, stream>>>(rowPart, gcursR, dinv);
        colB_kernel<<<NBUCK, 256, 0, stream>>>(colPart, gcursC, dinv, offs, ecnt,
                                               edgesOut);
        gather_kernel<<<(N_NODES + 3) / 4, 256, 0, stream>>>(offs, ecnt, edgesOut,
                                                             dinv, xb, Sb);
        fused_mfma<<<NPAD / 64, 256, 0, stream>>>(xb, Sb, wzT, whT, wlT,
                                                  bxz, bhz, bxh, bhh, blin, outp);
    } else {
        float* deg = (float*)d_ws;
        float* dv  = deg + NPAD;
        hipMemsetAsync(deg, 0, (size_t)NPAD * sizeof(float), stream);
        hipMemsetAsync(d_out, 0, (size_t)N_NODES * F * sizeof(float), stream);
        deg_fb<<<(N_EDGES + 255) / 256, 256, 0, stream>>>(ei, ew, deg);
        dinv_kernel<<<(N_NODES + 255) / 256, 256, 0, stream>>>(deg, dv);
        scatter_fb<<<N_EDGES / 4, 256, 0, stream>>>(ei, ew, x, dv, outp);
        fused_fp32<<<(N_NODES + BN - 1) / BN, 128, 0, stream>>>(
            x, outp, Wxz0, Wxz1, Wxh0, Wxh1, bxz, bhz, bxh, bhh, Wlin, blin);
    }
}

// Round 15
// 104.684 us; speedup vs baseline: 1.8627x; 1.0437x over previous
//
#include <hip/hip_runtime.h>

#define N_NODES 50000
#define N_EDGES 800000
#define F 64
#define NPAD 50048                       // N_NODES padded to multiple of 64
#define NBUCK 196                        // node buckets of 256 (50176 >= 50000)
#define NBLK 256                         // build blocks
#define EPB (N_EDGES / NBLK)             // 3125 edges per build block
#define CAP 5120                         // slots per bucket region (mean 4096 + 16 sigma)
#define BN 128                           // fallback fused block
#define AIDX32(k, n) ((k) * 132 + ((k) >> 3) * 4 + (n))

typedef float f32x4 __attribute__((ext_vector_type(4)));
typedef short bf16x8 __attribute__((ext_vector_type(8)));

__device__ inline unsigned short f2bf(float f) {
    unsigned u = __float_as_uint(f);
    u = (u + 0x7FFFu + ((u >> 16) & 1u)) >> 16;
    return (unsigned short)u;
}
__device__ inline float bf2f(unsigned short u) {
    return __uint_as_float((unsigned)u << 16);
}

// ---- P: weights -> bf16 [f][k] panels; x -> bf16; init bucket cursors ----
__global__ __launch_bounds__(256) void prep_kernel(
    const float* __restrict__ x,
    const float* __restrict__ Wxz0, const float* __restrict__ Wxz1,
    const float* __restrict__ Wxh0, const float* __restrict__ Wxh1,
    const float* __restrict__ Wlin,
    unsigned short* __restrict__ xb, unsigned short* __restrict__ wzT,
    unsigned short* __restrict__ whT, unsigned short* __restrict__ wlT,
    int* __restrict__ gcursC, int* __restrict__ gcursR) {
    int blk = blockIdx.x;
    int t = threadIdx.x;
    if (blk < 80) {
        int gid = blk * 256 + t;
        int m = gid >> 12, idx = gid & 4095;
        int k = idx >> 6, f = idx & 63;
        const float* src;
        unsigned short* dst;
        if (m == 0)      { src = Wxz0; dst = wzT; }
        else if (m == 1) { src = Wxz1; dst = wzT + 4096; }
        else if (m == 2) { src = Wxh0; dst = whT; }
        else if (m == 3) { src = Wxh1; dst = whT + 4096; }
        else             { src = Wlin; dst = wlT; }
        dst[f * 64 + k] = f2bf(src[idx]);
    } else if (blk < 80 + NPAD * 16 / 256) {
        int idx4 = (blk - 80) * 256 + t;             // NPAD*16 items
        int n = idx4 >> 4;
        ushort4 o = make_ushort4(0, 0, 0, 0);
        if (n < N_NODES) {
            float4 v = *(const float4*)&x[idx4 * 4];
            o = make_ushort4(f2bf(v.x), f2bf(v.y), f2bf(v.z), f2bf(v.w));
        }
        *(ushort4*)&xb[idx4 * 4] = o;
    } else {                                          // init bucket cursors
        for (int i = t; i < NBUCK; i += 256) {
            gcursC[i] = i * CAP;
            gcursR[i] = i * CAP;
        }
    }
}

// ---- K1: fused histogram + space-reserve + placement; edges cached in LDS ----
__global__ __launch_bounds__(256) void build_kernel(const int* __restrict__ ei,
                                                    const float* __restrict__ ew,
                                                    int* __restrict__ gcursC,
                                                    int* __restrict__ gcursR,
                                                    uint2* __restrict__ colPart,
                                                    uint2* __restrict__ rowPart) {
    __shared__ int histC[NBUCK], histR[NBUCK];
    __shared__ int cursC[NBUCK], cursR[NBUCK];
    __shared__ unsigned ecRC[EPB];                    // r<<16 | c (both < 65536)
    __shared__ float    ecW[EPB];                     // 25 KB total edge cache
    const int t = threadIdx.x, blk = blockIdx.x;
    for (int i = t; i < NBUCK; i += 256) { histC[i] = 0; histR[i] = 0; }
    __syncthreads();
    const int e0 = blk * EPB;
    // pass 1: read edges ONCE, cache in LDS, local histograms
    for (int i = t; i < EPB; i += 256) {
        int e = e0 + i;
        int r = ei[e], c = ei[N_EDGES + e];
        ecRC[i] = ((unsigned)r << 16) | (unsigned)c;
        ecW[i] = ew[e];
        if (r != c) {
            atomicAdd(&histC[c >> 8], 1);
            atomicAdd(&histR[r >> 8], 1);
        }
    }
    __syncthreads();
    // reserve space: one global atomic per (block,bucket) on 392 hot lines
    for (int i = t; i < NBUCK; i += 256) {
        cursC[i] = atomicAdd(&gcursC[i], histC[i]);
        cursR[i] = atomicAdd(&gcursR[i], histR[i]);
    }
    __syncthreads();
    // pass 2: scatter from LDS cache into reserved ranges
    for (int i = t; i < EPB; i += 256) {
        unsigned rc = ecRC[i];
        int r = rc >> 16, c = rc & 0xFFFF;
        if (r == c) continue;
        unsigned wbits = __float_as_uint(ecW[i]);
        int bC = c >> 8, bR = r >> 8;
        int pC = atomicAdd(&cursC[bC], 1);
        if (pC < (bC + 1) * CAP)                      // clamp (never hit)
            colPart[pC] = make_uint2((unsigned)r | ((unsigned)(c & 255) << 16), wbits);
        int pR = atomicAdd(&cursR[bR], 1);
        if (pR < (bR + 1) * CAP)
            rowPart[pR] = make_uint2((unsigned)(r & 255), wbits);
    }
}

// ---- K2: per-bucket deg reduction (LDS fp32) -> dinv ----
__global__ __launch_bounds__(256) void rowB_kernel(const uint2* __restrict__ rowPart,
                                                   const int* __restrict__ gcursR,
                                                   float* __restrict__ dinv) {
    __shared__ float degL[256];
    const int t = threadIdx.x, b = blockIdx.x;
    degL[t] = 0.0f;
    __syncthreads();
    const int start = b * CAP, end = gcursR[b];
    for (int i = start + t; i < end; i += 256) {
        uint2 v = rowPart[i];
        atomicAdd(&degL[v.x], __uint_as_float(v.y));
    }
    __syncthreads();
    int n = b * 256 + t;
    if (n < N_NODES) {
        float d = degL[t];
        dinv[n] = (d > 0.0f) ? rsqrtf(d) : 0.0f;
    }
}

// ---- K3: per-bucket CSR build; bucket cached in LDS; packed 4B edgesOut ----
__global__ __launch_bounds__(256) void colB_kernel(const uint2* __restrict__ colPart,
                                                   const int* __restrict__ gcursC,
                                                   const float* __restrict__ dinv,
                                                   int* __restrict__ offs,
                                                   int* __restrict__ ecnt,
                                                   unsigned* __restrict__ edgesOut) {
    __shared__ uint2 ecache[CAP];                     // 40 KB bucket cache
    __shared__ int cntL[256];
    __shared__ int curL[256];
    __shared__ int wsum[4];
    const int t = threadIdx.x, b = blockIdx.x;
    const int lane = t & 63, wid = t >> 6;
    const int start = b * CAP, end = gcursC[b];
    const int m = end - start;
    cntL[t] = 0;
    __syncthreads();
    for (int i = t; i < m; i += 256) {                // read bucket ONCE
        uint2 v = colPart[start + i];
        ecache[i] = v;
        atomicAdd(&cntL[(v.x >> 16) & 255], 1);
    }
    __syncthreads();
    int v = cntL[t];
    int s = v;
#pragma unroll
    for (int d = 1; d < 64; d <<= 1) {
        int u = __shfl_up(s, d);
        if (lane >= d) s += u;
    }
    if (lane == 63) wsum[wid] = s;
    __syncthreads();
    int wbase = 0;
    for (int w = 0; w < wid; ++w) wbase += wsum[w];
    int excl = wbase + s - v;
    curL[t] = excl;
    int n = b * 256 + t;
    if (n < N_NODES) { offs[n] = start + excl; ecnt[n] = v; }
    __syncthreads();
    for (int i = t; i < m; i += 256) {                // place from LDS
        uint2 e = ecache[i];
        int cl = (e.x >> 16) & 255;
        int p = atomicAdd(&curL[cl], 1);
        int r = e.x & 0xFFFF;
        float wd = __uint_as_float(e.y) * dinv[r];
        edgesOut[start + p] = (unsigned)r | ((unsigned)f2bf(wd) << 16);
    }
}

// ---- K4: CSR gather in bf16, wave-uniform loop, 4B packed edges ----
__global__ __launch_bounds__(256) void gather_kernel(const int* __restrict__ offs,
                                                     const int* __restrict__ ecnt,
                                                     const unsigned* __restrict__ edgesOut,
                                                     const float* __restrict__ dinv,
                                                     const unsigned short* __restrict__ xb,
                                                     unsigned short* __restrict__ Sb) {
    int n = blockIdx.x * 4 + (threadIdx.x >> 6);
    int lane = threadIdx.x & 63;
    if (n >= N_NODES) return;
    const int half = lane >> 5, hl = lane & 31;
    int p = offs[n];
    int end = p + ecnt[n];                            // exact count: no slack
    float acc0 = 0.0f, acc1 = 0.0f;
    for (int base = p; base < end; base += 64) {
        int rem = end - base;
        unsigned ev = 0u;
        if (lane < rem) ev = edgesOut[base + lane];   // 256B coalesced
        int myr = (int)(ev & 0xFFFFu);
        float mwd = bf2f((unsigned short)(ev >> 16));
        int cnt = min(rem, 64);
        int j = 0;
        for (; j + 8 <= cnt; j += 8) {                // 4 edges per half
            int sA = j + half,     sB = j + 2 + half;
            int sC = j + 4 + half, sD = j + 6 + half;
            int   rA = __shfl(myr, sA); float wA = __shfl(mwd, sA);
            int   rB = __shfl(myr, sB); float wB = __shfl(mwd, sB);
            int   rC = __shfl(myr, sC); float wC = __shfl(mwd, sC);
            int   rD = __shfl(myr, sD); float wD = __shfl(mwd, sD);
            ushort2 xA = *(const ushort2*)&xb[(size_t)rA * F + hl * 2];
            ushort2 xB = *(const ushort2*)&xb[(size_t)rB * F + hl * 2];
            ushort2 xC = *(const ushort2*)&xb[(size_t)rC * F + hl * 2];
            ushort2 xD = *(const ushort2*)&xb[(size_t)rD * F + hl * 2];
            acc0 = fmaf(wA, bf2f(xA.x), acc0); acc1 = fmaf(wA, bf2f(xA.y), acc1);
            acc0 = fmaf(wB, bf2f(xB.x), acc0); acc1 = fmaf(wB, bf2f(xB.y), acc1);
            acc0 = fmaf(wC, bf2f(xC.x), acc0); acc1 = fmaf(wC, bf2f(xC.y), acc1);
            acc0 = fmaf(wD, bf2f(xD.x), acc0); acc1 = fmaf(wD, bf2f(xD.y), acc1);
        }
        for (; j < cnt; j += 2) {                     // uniform tail
            int s = j + half;
            int r = __shfl(myr, s);
            float wd = __shfl(mwd, s);
            ushort2 xv = *(const ushort2*)&xb[(size_t)r * F + hl * 2];
            acc0 = fmaf(wd, bf2f(xv.x), acc0);
            acc1 = fmaf(wd, bf2f(xv.y), acc1);
        }
    }
    acc0 += __shfl_xor(acc0, 32);
    acc1 += __shfl_xor(acc1, 32);
    if (half == 0) {
        float s = -dinv[n];
        ushort2 o = make_ushort2(f2bf(s * acc0), f2bf(s * acc1));
        *(ushort2*)&Sb[(size_t)n * F + hl * 2] = o;
    }
}

// ---- K5: MFMA fused kernel. 4 waves/block, 16 nodes/wave, no barriers ----
__global__ __launch_bounds__(256) void fused_mfma(
    const unsigned short* __restrict__ xb, const unsigned short* __restrict__ Sb,
    const unsigned short* __restrict__ wzT, const unsigned short* __restrict__ whT,
    const unsigned short* __restrict__ wlT,
    const float* __restrict__ bxz, const float* __restrict__ bhz,
    const float* __restrict__ bxh, const float* __restrict__ bhh,
    const float* __restrict__ blin, float* __restrict__ out) {
    __shared__ __align__(16) unsigned short Rlds[4 * 16 * 72];  // 9.2 KB

    const int t = threadIdx.x;
    const int l = t & 63, wid = t >> 6;
    const int row16 = l & 15, quad = l >> 4;
    const int gn0 = blockIdx.x * 64 + wid * 16;

    f32x4 zacc[4], hacc[4];
#pragma unroll
    for (int ft = 0; ft < 4; ++ft) {
        int f = ft * 16 + row16;
        float bz = bxz[f] + bhz[f];
        float bh = bxh[f] + bhh[f];
        zacc[ft] = (f32x4){bz, bz, bz, bz};
        hacc[ft] = (f32x4){bh, bh, bh, bh};
    }

#pragma unroll
    for (int half = 0; half < 2; ++half) {
        const unsigned short* Ab = half ? Sb : xb;
        const unsigned short* Wzp = wzT + half * 4096;
        const unsigned short* Whp = whT + half * 4096;
#pragma unroll
        for (int ks = 0; ks < 2; ++ks) {
            bf16x8 a = *(const bf16x8*)(Ab + (size_t)(gn0 + row16) * 64 + ks * 32 + quad * 8);
#pragma unroll
            for (int ft = 0; ft < 4; ++ft) {
                bf16x8 bz8 = *(const bf16x8*)(Wzp + (ft * 16 + row16) * 64 + ks * 32 + quad * 8);
                bf16x8 bh8 = *(const bf16x8*)(Whp + (ft * 16 + row16) * 64 + ks * 32 + quad * 8);
                zacc[ft] = __builtin_amdgcn_mfma_f32_16x16x32_bf16(a, bz8, zacc[ft], 0, 0, 0);
                hacc[ft] = __builtin_amdgcn_mfma_f32_16x16x32_bf16(a, bh8, hacc[ft], 0, 0, 0);
            }
        }
    }

#pragma unroll
    for (int ft = 0; ft < 4; ++ft)
#pragma unroll
        for (int r = 0; r < 4; ++r) {
            float z = zacc[ft][r], h = hacc[ft][r];
            float zz = 1.0f / (1.0f + __expf(-z));
            float R = fmaxf((1.0f - zz) * tanhf(h), 0.0f);
            Rlds[wid * 1152 + (quad * 4 + r) * 72 + ft * 16 + row16] = f2bf(R);
        }

    f32x4 oacc[4];
#pragma unroll
    for (int ft = 0; ft < 4; ++ft) oacc[ft] = (f32x4){0.f, 0.f, 0.f, 0.f};
#pragma unroll
    for (int ks = 0; ks < 2; ++ks) {
        bf16x8 ra = *(const bf16x8*)&Rlds[wid * 1152 + row16 * 72 + ks * 32 + quad * 8];
#pragma unroll
        for (int ft = 0; ft < 4; ++ft) {
            bf16x8 wl8 = *(const bf16x8*)(wlT + (ft * 16 + row16) * 64 + ks * 32 + quad * 8);
            oacc[ft] = __builtin_amdgcn_mfma_f32_16x16x32_bf16(ra, wl8, oacc[ft], 0, 0, 0);
        }
    }
#pragma unroll
    for (int ft = 0; ft < 4; ++ft) {
        float bl = blin[ft * 16 + row16];
#pragma unroll
        for (int r = 0; r < 4; ++r) {
            int gn = gn0 + quad * 4 + r;
            if (gn < N_NODES) out[gn * 64 + ft * 16 + row16] = oacc[ft][r] + bl;
        }
    }
}

// ======================= fallback path (ws too small) =======================
__global__ __launch_bounds__(256) void deg_fb(const int* __restrict__ ei,
                                              const float* __restrict__ ew,
                                              float* __restrict__ deg) {
    int e = blockIdx.x * blockDim.x + threadIdx.x;
    if (e >= N_EDGES) return;
    int r = ei[e];
    int c = ei[N_EDGES + e];
    if (r != c) atomicAdd(&deg[r], ew[e]);
}

__global__ __launch_bounds__(256) void dinv_kernel(const float* __restrict__ deg,
                                                   float* __restrict__ dinv) {
    int n = blockIdx.x * blockDim.x + threadIdx.x;
    if (n >= N_NODES) return;
    float d = deg[n];
    dinv[n] = (d > 0.0f) ? rsqrtf(d) : 0.0f;
}

__global__ __launch_bounds__(256) void scatter_fb(const int* __restrict__ ei,
                                                  const float* __restrict__ ew,
                                                  const float* __restrict__ x,
                                                  const float* __restrict__ dinv,
                                                  float* S) {
    int e = blockIdx.x * 4 + (threadIdx.x >> 6);
    int lane = threadIdx.x & 63;
    if (e >= N_EDGES) return;
    int r = ei[e];
    int c = ei[N_EDGES + e];
    if (r == c) return;
    float nrm = -dinv[r] * ew[e] * dinv[c];
    atomicAdd(&S[c * F + lane], nrm * x[r * F + lane]);
}

__global__ __launch_bounds__(128) void fused_fp32(
    const float* __restrict__ x, float* sOut,
    const float* __restrict__ Wxz0, const float* __restrict__ Wxz1,
    const float* __restrict__ Wxh0, const float* __restrict__ Wxh1,
    const float* __restrict__ bxz, const float* __restrict__ bhz,
    const float* __restrict__ bxh, const float* __restrict__ bhh,
    const float* __restrict__ Wlin, const float* __restrict__ blin) {
    __shared__ float P[8448];
    float* As = P;
    float* Wc = P + 4352;
    const int t = threadIdx.x;
    const int n0 = blockIdx.x * BN;
    const int ti = t >> 3;
    const int tj = t & 7;
    const int nb = ti * 8;
    const int f0 = tj * 8;

    float zacc[8][8], hacc[8][8];
#pragma unroll
    for (int j = 0; j < 8; ++j) {
        float bz = bxz[f0 + j] + bhz[f0 + j];
        float bh = bxh[f0 + j] + bhh[f0 + j];
#pragma unroll
        for (int i = 0; i < 8; ++i) { zacc[i][j] = bz; hacc[i][j] = bh; }
    }
    for (int half = 0; half < 2; ++half) {
        const float* Abase = half ? (const float*)sOut : x;
        const float* Wz = half ? Wxz1 : Wxz0;
        const float* Wh = half ? Wxh1 : Wxh0;
        for (int kc = 0; kc < 2; ++kc) {
            const int kb = kc * 32;
            __syncthreads();
#pragma unroll
            for (int rep = 0; rep < 8; ++rep) {
                int idx = rep * 128 + t;
                int nn = idx >> 3;
                int q = idx & 7;
                int gn = n0 + nn;
                float4 v = make_float4(0.f, 0.f, 0.f, 0.f);
                if (gn < N_NODES) v = *(const float4*)&Abase[gn * F + kb + q * 4];
                int k = q * 4;
                As[AIDX32(k + 0, nn)] = v.x;
                As[AIDX32(k + 1, nn)] = v.y;
                As[AIDX32(k + 2, nn)] = v.z;
                As[AIDX32(k + 3, nn)] = v.w;
            }
#pragma unroll
            for (int rep = 0; rep < 8; ++rep) {
                int idx = rep * 128 + t;
                int cq = idx & 31;
                int kk = idx >> 5;
                const float* src = (cq < 16) ? &Wz[(kb + kk) * F + cq * 4]
                                             : &Wh[(kb + kk) * F + (cq - 16) * 4];
                *(float4*)&Wc[kk * 128 + cq * 4] = *(const float4*)src;
            }
            __syncthreads();
#pragma unroll 8
            for (int kl = 0; kl < 32; ++kl) {
                const float* Ap = &As[AIDX32(kl, nb)];
                float4 a0 = *(const float4*)Ap;
                float4 a1 = *(const float4*)(Ap + 4);
                const float* Wp = &Wc[kl * 128 + f0];
                float4 wz0 = *(const float4*)Wp;
                float4 wz1 = *(const float4*)(Wp + 4);
                float4 wh0 = *(const float4*)(Wp + 64);
                float4 wh1 = *(const float4*)(Wp + 68);
                float a[8]  = {a0.x, a0.y, a0.z, a0.w, a1.x, a1.y, a1.z, a1.w};
                float wz[8] = {wz0.x, wz0.y, wz0.z, wz0.w, wz1.x, wz1.y, wz1.z, wz1.w};
                float wh[8] = {wh0.x, wh0.y, wh0.z, wh0.w, wh1.x, wh1.y, wh1.z, wh1.w};
#pragma unroll
                for (int i = 0; i < 8; ++i)
#pragma unroll
                    for (int j = 0; j < 8; ++j) {
                        zacc[i][j] = fmaf(a[i], wz[j], zacc[i][j]);
                        hacc[i][j] = fmaf(a[i], wh[j], hacc[i][j]);
                    }
            }
        }
    }
    __syncthreads();
#pragma unroll
    for (int j = 0; j < 8; ++j) {
        int f = f0 + j;
        float R[8];
#pragma unroll
        for (int i = 0; i < 8; ++i) {
            float zz = 1.0f / (1.0f + __expf(-zacc[i][j]));
            float hh = tanhf(hacc[i][j]);
            R[i] = fmaxf((1.0f - zz) * hh, 0.0f);
        }
        float* Rp = &P[f * 132 + nb];
        *(float4*)Rp = make_float4(R[0], R[1], R[2], R[3]);
        *(float4*)(Rp + 4) = make_float4(R[4], R[5], R[6], R[7]);
    }
    __syncthreads();
    float (*oacc)[8] = zacc;
#pragma unroll
    for (int j = 0; j < 8; ++j) {
        float bl = blin[f0 + j];
#pragma unroll
        for (int i = 0; i < 8; ++i) oacc[i][j] = bl;
    }
#pragma unroll 4
    for (int k = 0; k < 64; ++k) {
        const float* Rp = &P[k * 132 + nb];
        float4 a0 = *(const float4*)Rp;
        float4 a1 = *(const float4*)(Rp + 4);
        float4 w0 = *(const float4*)&Wlin[k * F + f0];
        float4 w1 = *(const float4*)&Wlin[k * F + f0 + 4];
        float a[8] = {a0.x, a0.y, a0.z, a0.w, a1.x, a1.y, a1.z, a1.w};
        float w[8] = {w0.x, w0.y, w0.z, w0.w, w1.x, w1.y, w1.z, w1.w};
#pragma unroll
        for (int i = 0; i < 8; ++i)
#pragma unroll
            for (int j = 0; j < 8; ++j)
                oacc[i][j] = fmaf(a[i], w[j], oacc[i][j]);
    }
#pragma unroll
    for (int i = 0; i < 8; ++i) {
        int gn = n0 + nb + i;
        if (gn < N_NODES) {
            *(float4*)&sOut[gn * F + f0] =
                make_float4(oacc[i][0], oacc[i][1], oacc[i][2], oacc[i][3]);
            *(float4*)&sOut[gn * F + f0 + 4] =
                make_float4(oacc[i][4], oacc[i][5], oacc[i][6], oacc[i][7]);
        }
    }
}

extern "C" void kernel_launch(void* const* d_in, const int* in_sizes, int n_in,
                              void* d_out, int out_size, void* d_ws, size_t ws_size,
                              hipStream_t stream) {
    const float* x    = (const float*)d_in[0];
    const int*   ei   = (const int*)d_in[1];
    const float* ew   = (const float*)d_in[2];
    const float* Wxz0 = (const float*)d_in[3];
    const float* Wxz1 = (const float*)d_in[4];
    const float* bxz  = (const float*)d_in[5];
    const float* bhz  = (const float*)d_in[8];
    const float* Wxh0 = (const float*)d_in[15];
    const float* Wxh1 = (const float*)d_in[16];
    const float* bxh  = (const float*)d_in[17];
    const float* bhh  = (const float*)d_in[20];
    const float* Wlin = (const float*)d_in[21];
    const float* blin = (const float*)d_in[22];
    float* outp = (float*)d_out;

    int*    gcursC = (int*)d_ws;                 // NBUCK
    int*    gcursR = gcursC + 256;               // NBUCK
    int*    offs   = gcursR + 256;               // NPAD
    int*    ecnt   = offs + NPAD;                // NPAD
    float*  dinv   = (float*)(ecnt + NPAD);      // NPAD
    unsigned short* xb  = (unsigned short*)(dinv + NPAD);
    unsigned short* Sb  = xb + (size_t)NPAD * 64;
    unsigned short* wzT = Sb + (size_t)NPAD * 64;
    unsigned short* whT = wzT + 8192;
    unsigned short* wlT = whT + 8192;
    uint2*    colPart  = (uint2*)(wlT + 4096);
    uint2*    rowPart  = colPart + (size_t)NBUCK * CAP;
    unsigned* edgesOut = (unsigned*)(rowPart + (size_t)NBUCK * CAP);
    size_t needed = (size_t)(512 + NPAD * 3) * 4
                  + (size_t)NPAD * 64 * 2 * 2 + 40960
                  + (size_t)NBUCK * CAP * (8 + 8 + 4) + 256;

    if (ws_size >= needed) {
        prep_kernel<<<80 + NPAD * 16 / 256 + 1, 256, 0, stream>>>(
            x, Wxz0, Wxz1, Wxh0, Wxh1, Wlin, xb, wzT, whT, wlT, gcursC, gcursR);
        build_kernel<<<NBLK, 256, 0, stream>>>(ei, ew, gcursC, gcursR,
                                               colPart, rowPart);
        rowB_kernel<<<NBUCK, 256, 0, stream>>>(rowPart, gcursR, dinv);
        colB_kernel<<<NBUCK, 256, 0, stream>>>(colPart, gcursC, dinv, offs, ecnt,
                                               edgesOut);
        gather_kernel<<<(N_NODES + 3) / 4, 256, 0, stream>>>(offs, ecnt, edgesOut,
                                                             dinv, xb, Sb);
        fused_mfma<<<NPAD / 64, 256, 0, stream>>>(xb, Sb, wzT, whT, wlT,
                                                  bxz, bhz, bxh, bhh, blin, outp);
    } else {
        float* deg = (float*)d_ws;
        float* dv  = deg + NPAD;
        hipMemsetAsync(deg, 0, (size_t)NPAD * sizeof(float), stream);
        hipMemsetAsync(d_out, 0, (size_t)N_NODES * F * sizeof(float), stream);
        deg_fb<<<(N_EDGES + 255) / 256, 256, 0, stream>>>(ei, ew, deg);
        dinv_kernel<<<(N_NODES + 255) / 256, 256, 0, stream>>>(deg, dv);
        scatter_fb<<<N_EDGES / 4, 256, 0, stream>>>(ei, ew, x, dv, outp);
        fused_fp32<<<(N_NODES + BN - 1) / BN, 128, 0, stream>>>(
            x, outp, Wxz0, Wxz1, Wxh0, Wxh1, bxz, bhz, bxh, bhh, Wlin, blin);
    }
}